// Round 12
// baseline (521.846 us; speedup 1.0000x reference)
//
#include <hip/hip_runtime.h>
#include <cstdint>

#define NB 32
#define NBW 16
#define IC 2048
#define IK 16
#define OC 64
#define OD 32
#define ODF (OC*OD)          // 2048 flattened od
#define NCH 256              // i-chunks
#define CHUNK (IC/NCH)       // 8
#define PARTBLK (NBW*ODF)    // 32768 floats per slot
#define NSLOT (NCH*2)        // 512 wgs

typedef __fp16 h2 __attribute__((ext_vector_type(2)));
typedef __fp16 h8 __attribute__((ext_vector_type(8)));
typedef float  f4 __attribute__((ext_vector_type(4)));

__device__ __forceinline__ h2 pk2(float a, float b) {
#if __has_builtin(__builtin_amdgcn_cvt_pkrtz)
  return __builtin_amdgcn_cvt_pkrtz(a, b);
#else
  h2 r; r.x = (__fp16)a; r.y = (__fp16)b; return r;
#endif
}
__device__ __forceinline__ unsigned int bcu(h2 v){ return __builtin_bit_cast(unsigned int, v); }
__device__ __forceinline__ h8 bch8(uint4 u){ return __builtin_bit_cast(h8, u); }

__device__ __forceinline__ f4 mfma_16x16x32(h8 a, h8 b, f4 c) {
  return __builtin_amdgcn_mfma_f32_16x16x32_f16(a, b, c, 0, 0, 0);
}

// MFMA routing pass, single W stream + LDS W-replay.
// R10: fused per-i softmax at 1 wg/CU = 154us (sync/latency). R11: phase-split
// re-read W from HBM = 208us (FETCH 2x). Fix: P1 stores the converted f16 W
// fragments in a 64 KB LDS tile; P3 replays them from LDS (no 2nd HBM stream)
// and accumulates s in REGISTERS (acc[8], like the 30us pass0 GEMM).
// LDS 76.3 KB -> 2 wg/CU; grid 512 (CHUNK=8), twins XCD-grouped.
// Per i (ITER>0): P1 u=mfma(W,x), dot v, reduce -> agr | BAR | P2 softmax
// (wave w = batch row w) -> c_s | BAR | P3 u=mfma(W_lds,x), acc += c*u | BAR.
template<int ITER>
__global__ __launch_bounds__(1024)
void caps_pass(const float* __restrict__ xg, const float* __restrict__ Wg,
               const float* __restrict__ vin, const float* __restrict__ binT,
               float* __restrict__ boutT, float* __restrict__ part)
{
  __shared__ uint4 x_h[8][2][16];                       // 4 KB packed-f16 x
  __shared__ uint4 W_lds[(ITER==0)?1:4096];             // 64 KB f16 W replay
  __shared__ float agr[(ITER==0)?1:(64*17)];            // 4.25 KB [o][b]
  __shared__ float c_s[(ITER==0)?1:(16*65)];            // 4.06 KB [b][o]

  const int t  = threadIdx.x;       // 0..1023
  const int w  = t >> 6;            // wave 0..15
  const int l  = t & 63;
  const int lb = l & 15;            // tile col (b) / A row (od)
  const int lg = l >> 4;            // lane group 0..3

  // bid%8 = XCD; twin pair (bh 0/1) of one ci lands on the same XCD's L2.
  const int bid  = blockIdx.x;
  const int slot = bid >> 3;        // 0..63
  const int bh   = slot & 1;
  const int ci   = (bid & 7) * 32 + (slot >> 1);   // 0..255
  const int i0   = ci * CHUNK;
  const int bg0  = bh * NBW;
  const f4 zf = {0.f, 0.f, 0.f, 0.f};

  f4 acc[8];
#pragma unroll
  for (int q = 0; q < 8; ++q) acc[q] = zf;

  // stage x[16 b][8 i][16 k] as f16, once (CHUNK == 8)
  if (t < 256) {
    const int si = t >> 5, kc = (t >> 4) & 1, sb = t & 15;
    const float* xp = &xg[((size_t)(bg0 + sb)*IC + (i0 + si))*IK + kc*8];
    const float4 xa = *(const float4*)xp;
    const float4 xb = *(const float4*)(xp + 4);
    uint4 u;
    u.x = bcu(pk2(xa.x, xa.y)); u.y = bcu(pk2(xa.z, xa.w));
    u.z = bcu(pk2(xb.x, xb.y)); u.w = bcu(pk2(xb.z, xb.w));
    x_h[si][kc][sb] = u;
  }
  __syncthreads();

  if (ITER == 0) {
#pragma unroll 1
    for (int p = 0; p < 4; ++p) {             // pair of i per MFMA (K=32)
      const int isel = lg >> 1, kc = lg & 1;
      const int il = p*2 + isel;
      const h8 B = bch8(x_h[il][kc][lb]);
      const size_t wbase = ((size_t)(i0 + il)*ODF + lb)*IK + kc*8;
#pragma unroll
      for (int tt = 0; tt < 8; ++tt) {
        const float* wp = &Wg[wbase + (size_t)((w*8 + tt)*16)*IK];
        const float4 wa = *(const float4*)wp;
        const float4 wb = *(const float4*)(wp + 4);
        uint4 au;
        au.x = bcu(pk2(wa.x, wa.y)); au.y = bcu(pk2(wa.z, wa.w));
        au.z = bcu(pk2(wb.x, wb.y)); au.w = bcu(pk2(wb.z, wb.w));
        acc[tt] = mfma_16x16x32(bch8(au), B, acc[tt]);
      }
    }
  } else {
#pragma unroll 1
    for (int ii = 0; ii < 8; ++ii) {
      const int i = i0 + ii;
      // ---- P1: u via MFMA from global W (convert + stash f16 in LDS) ----
      uint4 bu = {0u,0u,0u,0u};
      if (lg < 2) bu = x_h[ii][lg][lb];       // real K half; rest zero-pad
      const h8 B = bch8(bu);
      float ap[4] = {0.f, 0.f, 0.f, 0.f};
#pragma unroll
      for (int tt = 0; tt < 8; ++tt) {
        const int tile = w*8 + tt;
        uint4 au = {0u,0u,0u,0u};
        if (lg < 2) {
          const float* wp = &Wg[((size_t)i*ODF + tile*16 + lb)*IK + lg*8];
          const float4 wa = *(const float4*)wp;
          const float4 wb = *(const float4*)(wp + 4);
          au.x = bcu(pk2(wa.x, wa.y)); au.y = bcu(pk2(wa.z, wa.w));
          au.z = bcu(pk2(wb.x, wb.y)); au.w = bcu(pk2(wb.z, wb.w));
          W_lds[(tile*16 + lb)*2 + lg] = au;  // stash for P3 replay
        }
        const f4 u = mfma_16x16x32(bch8(au), B, zf);
        const int o = w*4 + (tt >> 1);
        const float4 vv = *(const float4*)
          &vin[((size_t)(bg0 + lb)*OC + o)*OD + (tt & 1)*16 + lg*4];
        ap[tt >> 1] += u.x*vv.x + u.y*vv.y + u.z*vv.z + u.w*vv.w;
      }
#pragma unroll
      for (int q = 0; q < 4; ++q) {           // sum the 4 d-lane-groups
        float a = ap[q];
        a += __shfl_xor(a, 16);
        a += __shfl_xor(a, 32);
        if (l < 16) {
          const int o = w*4 + q;
          float bn = a;
          if (ITER == 2) bn += binT[((size_t)i*OC + o)*NB + bg0 + lb];
          if (ITER == 1) boutT[((size_t)i*OC + o)*NB + bg0 + lb] = bn;
          agr[o*17 + lb] = bn;
        }
      }
      __syncthreads();
      // ---- P2: softmax over o, wave w handles batch row b = w ----
      {
        const float a = agr[l*17 + w];        // o = l
        float m = a;
#pragma unroll
        for (int off = 1; off < 64; off <<= 1) m = fmaxf(m, __shfl_xor(m, off));
        const float e = __expf(a - m);
        float se = e;
#pragma unroll
        for (int off = 1; off < 64; off <<= 1) se += __shfl_xor(se, off);
        c_s[w*65 + l] = e / se;
      }
      __syncthreads();
      // ---- P3: replay W from LDS, accumulate s in regs ----
#pragma unroll
      for (int tt = 0; tt < 8; ++tt) {
        const int tile = w*8 + tt;
        uint4 au = {0u,0u,0u,0u};
        if (lg < 2) au = W_lds[(tile*16 + lb)*2 + lg];
        const f4 u = mfma_16x16x32(bch8(au), B, zf);
        const float cm = c_s[lb*65 + (w*4 + (tt >> 1))];
        acc[tt].x += cm*u.x; acc[tt].y += cm*u.y;
        acc[tt].z += cm*u.z; acc[tt].w += cm*u.w;
      }
      __syncthreads();                        // W_lds reused by next i's P1
    }
  }

  // flush partial s from regs (cells owned per-thread)
  const float scale = (ITER == 0) ? (1.0f/64.0f) : 1.0f;
  float* pp = part + (size_t)(ci*2 + bh)*PARTBLK;
#pragma unroll
  for (int tt = 0; tt < 8; ++tt) {
    float4 st;
    st.x = acc[tt].x*scale; st.y = acc[tt].y*scale;
    st.z = acc[tt].z*scale; st.w = acc[tt].w*scale;
    *(float4*)&pp[(size_t)lb*ODF + (w*8 + tt)*16 + lg*4] = st;
  }
}

// Sum the 256 i-chunk partials (per b-half) and apply squash.
// One 64-thr block per (b,o): lanes 0..31 = d, halves split the ci range.
__global__ __launch_bounds__(64)
void caps_reduce(const float* __restrict__ part, float* __restrict__ vout)
{
  const int r  = blockIdx.x;           // b*OC + o
  const int b  = r >> 6, o = r & 63;
  const int bh = b >> 4, bl = b & 15;
  const int d  = threadIdx.x & 31;
  const int h  = threadIdx.x >> 5;
  const float* p = part + (size_t)bh*PARTBLK + (size_t)bl*ODF + o*OD + d;
  float s = 0.f;
#pragma unroll 4
  for (int q = 0; q < NCH/2; ++q)
    s += p[(size_t)((h*(NCH/2) + q)*2)*PARTBLK];
  s += __shfl_xor(s, 32);
  float n2 = s*s;
#pragma unroll
  for (int off = 1; off < 32; off <<= 1) n2 += __shfl_xor(n2, off);
  const float n = sqrtf(n2);
  const float f = n2 / ((1.f + n2)*(n + 1e-8f));   // squash, matches ref
  if (h == 0) vout[(size_t)r*OD + d] = s*f;
}

extern "C" void kernel_launch(void* const* d_in, const int* in_sizes, int n_in,
                              void* d_out, int out_size, void* d_ws, size_t ws_size,
                              hipStream_t stream)
{
  const float* xg = (const float*)d_in[0];
  const float* Wg = (const float*)d_in[1];
  float* out = (float*)d_out;

  const size_t part_bytes = (size_t)NSLOT*PARTBLK*sizeof(float);  // 64 MB
  const size_t bbuf_bytes = (size_t)IC*OC*NB*sizeof(float);       // 16 MB
  float* part = (float*)d_ws;
  float* bbuf = (float*)((char*)d_ws + part_bytes);
  float* vbuf = (float*)((char*)bbuf + bbuf_bytes);
  (void)ws_size;

  // iter 1: c = 1/64 exactly -> pure GEMM, acc in regs
  caps_pass<0><<<NSLOT, 1024, 0, stream>>>(xg, Wg, nullptr, nullptr, nullptr, part);
  caps_reduce<<<NB*OC, 64, 0, stream>>>(part, vbuf);
  // iter 2: A1 = u.v1, c = softmax(A1); store A1 (transposed [i][o][b])
  caps_pass<1><<<NSLOT, 1024, 0, stream>>>(xg, Wg, vbuf, nullptr, bbuf, part);
  caps_reduce<<<NB*OC, 64, 0, stream>>>(part, vbuf);
  // iter 3: c = softmax(A1 + u.v2)
  caps_pass<2><<<NSLOT, 1024, 0, stream>>>(xg, Wg, vbuf, bbuf, nullptr, part);
  caps_reduce<<<NB*OC, 64, 0, stream>>>(part, out);
}

// Round 15
// 407.526 us; speedup vs baseline: 1.2805x; 1.2805x over previous
//
#include <hip/hip_runtime.h>
#include <cstdint>

#define NB 32
#define IC 2048
#define IK 16
#define OC 64
#define OD 32
#define ODF (OC*OD)          // 2048 flattened od
#define PARTBLK (16*ODF)     // 32768 floats per slot (16 local b)
#define NCH 128              // 16-i chunks for gemm0/saccum (grid 256)
#define NSLOT (NCH*2)

typedef __fp16 h2 __attribute__((ext_vector_type(2)));
typedef __fp16 h8 __attribute__((ext_vector_type(8)));
typedef float  f4 __attribute__((ext_vector_type(4)));

__device__ __forceinline__ h2 pk2(float a, float b) {
#if __has_builtin(__builtin_amdgcn_cvt_pkrtz)
  return __builtin_amdgcn_cvt_pkrtz(a, b);
#else
  h2 r; r.x = (__fp16)a; r.y = (__fp16)b; return r;
#endif
}
__device__ __forceinline__ unsigned int bcu(h2 v){ return __builtin_bit_cast(unsigned int, v); }
__device__ __forceinline__ h8 bch8(uint4 u){ return __builtin_bit_cast(h8, u); }
__device__ __forceinline__ f4 mfma_16x16x32(h8 a, h8 b, f4 c) {
  return __builtin_amdgcn_mfma_f32_16x16x32_f16(a, b, c, 0, 0, 0);
}
__device__ __forceinline__ uint4 packw(const float* wp) {
  const float4 wa = *(const float4*)wp;
  const float4 wb = *(const float4*)(wp + 4);
  uint4 au;
  au.x = bcu(pk2(wa.x, wa.y)); au.y = bcu(pk2(wa.z, wa.w));
  au.z = bcu(pk2(wb.x, wb.y)); au.w = bcu(pk2(wb.z, wb.w));
  return au;
}

// R10-R12 lesson: fused softmax passes (per-i barriers over 16 waves +
// HBM-latency W loads) sit at 150-220us with NOTHING busy, while the
// barrier-free GEMM (this structure) runs ~30us. So: decouple. Every kernel
// below is a streaming pass0-clone; softmax lives in caps_agree with only
// 3 barriers per wg. Verified MFMA fragment math from R10 kept bit-identical.

// K0: iter-1 GEMM (c=1/64 exact). Two i per MFMA (K=32). If WH, also emits
// the packed-f16 W copy (bh==0 wgs only) that later passes stream at half BW.
template<int WH>
__global__ __launch_bounds__(1024)
void caps_gemm0(const float* __restrict__ xg, const float* __restrict__ Wg,
                uint4* __restrict__ Whg, float* __restrict__ part)
{
  __shared__ uint4 x_h[8][2][16];
  const int t = threadIdx.x, w = t >> 6, l = t & 63, lb = l & 15, lg = l >> 4;
  const int bid = blockIdx.x, slot = bid >> 3;
  const int bh = slot & 1;
  const int ci = (bid & 7)*16 + (slot >> 1);     // XCD-grouped twins
  const int i0 = ci*16, bg0 = bh*16;
  const f4 zf = {0.f,0.f,0.f,0.f};
  f4 acc[8];
#pragma unroll
  for (int q = 0; q < 8; ++q) acc[q] = zf;

  for (int g8 = 0; g8 < 16; g8 += 8) {
    if (g8) __syncthreads();
    if (t < 256) {
      const int si = t >> 5, kc = (t >> 4) & 1, sb = t & 15;
      const float* xp = &xg[((size_t)(bg0 + sb)*IC + (i0 + g8 + si))*IK + kc*8];
      x_h[si][kc][sb] = packw(xp);
    }
    __syncthreads();
#pragma unroll 1
    for (int p = 0; p < 4; ++p) {
      const int isel = lg >> 1, kc = lg & 1, il = p*2 + isel;
      const h8 B = bch8(x_h[il][kc][lb]);
#pragma unroll
      for (int tt = 0; tt < 8; ++tt) {
        const size_t widx = (size_t)(i0 + g8 + il)*ODF + (w*8 + tt)*16 + lb;
        const uint4 au = packw(&Wg[widx*IK + kc*8]);
        if (WH && bh == 0) Whg[widx*2 + kc] = au;
        acc[tt] = mfma_16x16x32(bch8(au), B, acc[tt]);
      }
    }
  }
  float* pp = part + (size_t)(ci*2 + bh)*PARTBLK;
#pragma unroll
  for (int tt = 0; tt < 8; ++tt) {
    float4 st;
    st.x = acc[tt].x*(1.f/64.f); st.y = acc[tt].y*(1.f/64.f);
    st.z = acc[tt].z*(1.f/64.f); st.w = acc[tt].w*(1.f/64.f);
    *(float4*)&pp[(size_t)lb*ODF + (w*8 + tt)*16 + lg*4] = st;
  }
}

// KA: agreement + softmax + coalesced c write. grid 512 (8-i chunks x 2 bh),
// 2 wg/CU = 32 waves. v hoisted out of the i loop (i-invariant). 3 barriers.
template<int ITER, int WH>
__global__ __launch_bounds__(1024)
void caps_agree(const float* __restrict__ xg, const float* __restrict__ Wg,
                const uint4* __restrict__ Whg, const float* __restrict__ vin,
                float* __restrict__ a1g, float* __restrict__ cg)
{
  __shared__ uint4 x_h[8][2][16];
  __shared__ float agr[8*64*17];                 // 34.8 KB [ii][o][b]
  const int t = threadIdx.x, w = t >> 6, l = t & 63, lb = l & 15, lg = l >> 4;
  const int bid = blockIdx.x, slot = bid >> 3;
  const int bh = slot & 1;
  const int ci8 = (bid & 7)*32 + (slot >> 1);    // 0..255
  const int i0 = ci8*8, bg0 = bh*16;
  const f4 zf = {0.f,0.f,0.f,0.f};

  if (t < 256) {
    const int si = t >> 5, kc = (t >> 4) & 1, sb = t & 15;
    const float* xp = &xg[((size_t)(bg0 + sb)*IC + (i0 + si))*IK + kc*8];
    x_h[si][kc][sb] = packw(xp);
  }
  float4 vr[8];                                  // v fragments, i-invariant
#pragma unroll
  for (int tt = 0; tt < 8; ++tt) {
    const int o = w*4 + (tt >> 1);
    vr[tt] = *(const float4*)
      &vin[((size_t)(bg0 + lb)*OC + o)*OD + (tt & 1)*16 + lg*4];
  }
  __syncthreads();

#pragma unroll 1
  for (int ii = 0; ii < 8; ++ii) {
    const int i = i0 + ii;
    uint4 bu = {0u,0u,0u,0u};
    if (lg < 2) bu = x_h[ii][lg][lb];
    const h8 B = bch8(bu);
    float ap[4] = {0.f,0.f,0.f,0.f};
#pragma unroll
    for (int tt = 0; tt < 8; ++tt) {
      uint4 au = {0u,0u,0u,0u};
      if (lg < 2) {
        const size_t widx = (size_t)i*ODF + (w*8 + tt)*16 + lb;
        au = WH ? Whg[widx*2 + lg] : packw(&Wg[widx*IK + lg*8]);
      }
      const f4 u = mfma_16x16x32(bch8(au), B, zf);
      ap[tt >> 1] += u.x*vr[tt].x + u.y*vr[tt].y + u.z*vr[tt].z + u.w*vr[tt].w;
    }
#pragma unroll
    for (int q = 0; q < 4; ++q) {
      float a = ap[q];
      a += __shfl_xor(a, 16);
      a += __shfl_xor(a, 32);
      if (l < 16) {
        const int o = w*4 + q;
        float bn = a;
        if (ITER == 2) bn += a1g[((size_t)i*OC + o)*NB + bg0 + lb];
        if (ITER == 1) a1g[((size_t)i*OC + o)*NB + bg0 + lb] = bn;
        agr[(ii*64 + o)*17 + lb] = bn;
      }
    }
  }
  __syncthreads();
  // batched softmax: 128 (i,b) rows, 8 per wave; c overwrites agr in place
#pragma unroll
  for (int r = 0; r < 8; ++r) {
    const int row = w*8 + r, si = row >> 4, b = row & 15;
    const float a = agr[(si*64 + l)*17 + b];     // o = l
    float m = a;
#pragma unroll
    for (int off = 1; off < 64; off <<= 1) m = fmaxf(m, __shfl_xor(m, off));
    const float e = __expf(a - m);
    float se = e;
#pragma unroll
    for (int off = 1; off < 64; off <<= 1) se += __shfl_xor(se, off);
    agr[(si*64 + l)*17 + b] = e / se;
  }
  __syncthreads();
  // coalesced c flush: [i][o][b], 64B segments
#pragma unroll
  for (int cc = 0; cc < 8; ++cc) {
    const int o = t >> 4, b2 = t & 15;
    cg[((size_t)(i0 + cc)*OC + o)*NB + bg0 + b2] = agr[(cc*64 + o)*17 + b2];
  }
}

// KB: s accumulation — streaming GEMM with per-(i,o,b) weight c from global
// (coalesced 64B, L2-hot). acc in regs, one barrier per x restage.
template<int WH>
__global__ __launch_bounds__(1024)
void caps_saccum(const float* __restrict__ xg, const float* __restrict__ Wg,
                 const uint4* __restrict__ Whg, const float* __restrict__ cg,
                 float* __restrict__ part)
{
  __shared__ uint4 x_h[8][2][16];
  const int t = threadIdx.x, w = t >> 6, l = t & 63, lb = l & 15, lg = l >> 4;
  const int bid = blockIdx.x, slot = bid >> 3;
  const int bh = slot & 1;
  const int ci = (bid & 7)*16 + (slot >> 1);
  const int i0 = ci*16, bg0 = bh*16;
  const f4 zf = {0.f,0.f,0.f,0.f};
  f4 acc[8];
#pragma unroll
  for (int q = 0; q < 8; ++q) acc[q] = zf;

  for (int g8 = 0; g8 < 16; g8 += 8) {
    if (g8) __syncthreads();
    if (t < 256) {
      const int si = t >> 5, kc = (t >> 4) & 1, sb = t & 15;
      const float* xp = &xg[((size_t)(bg0 + sb)*IC + (i0 + g8 + si))*IK + kc*8];
      x_h[si][kc][sb] = packw(xp);
    }
    __syncthreads();
#pragma unroll 1
    for (int ii = 0; ii < 8; ++ii) {
      const int i = i0 + g8 + ii;
      uint4 bu = {0u,0u,0u,0u};
      if (lg < 2) bu = x_h[ii][lg][lb];
      const h8 B = bch8(bu);
#pragma unroll
      for (int tt = 0; tt < 8; ++tt) {
        const int o = w*4 + (tt >> 1);
        uint4 au = {0u,0u,0u,0u};
        if (lg < 2) {
          const size_t widx = (size_t)i*ODF + (w*8 + tt)*16 + lb;
          au = WH ? Whg[widx*2 + lg] : packw(&Wg[widx*IK + lg*8]);
        }
        const f4 u = mfma_16x16x32(bch8(au), B, zf);
        const float cm = cg[((size_t)i*OC + o)*NB + bg0 + lb];
        acc[tt].x += cm*u.x; acc[tt].y += cm*u.y;
        acc[tt].z += cm*u.z; acc[tt].w += cm*u.w;
      }
    }
  }
  float* pp = part + (size_t)(ci*2 + bh)*PARTBLK;
#pragma unroll
  for (int tt = 0; tt < 8; ++tt) {
    float4 st; st.x = acc[tt].x; st.y = acc[tt].y; st.z = acc[tt].z; st.w = acc[tt].w;
    *(float4*)&pp[(size_t)lb*ODF + (w*8 + tt)*16 + lg*4] = st;
  }
}

// Sum the 256 slots and apply squash (R10-verified).
__global__ __launch_bounds__(64)
void caps_reduce(const float* __restrict__ part, float* __restrict__ vout)
{
  const int r  = blockIdx.x;           // b*OC + o
  const int b  = r >> 6, o = r & 63;
  const int bh = b >> 4, bl = b & 15;
  const int d  = threadIdx.x & 31;
  const int h  = threadIdx.x >> 5;
  const float* p = part + (size_t)bh*PARTBLK + (size_t)bl*ODF + o*OD + d;
  float s = 0.f;
#pragma unroll 4
  for (int q = 0; q < NCH/2; ++q)
    s += p[(size_t)((h*(NCH/2) + q)*2)*PARTBLK];
  s += __shfl_xor(s, 32);
  float n2 = s*s;
#pragma unroll
  for (int off = 1; off < 32; off <<= 1) n2 += __shfl_xor(n2, off);
  const float n = sqrtf(n2);
  const float f = n2 / ((1.f + n2)*(n + 1e-8f));
  if (h == 0) vout[(size_t)r*OD + d] = s*f;
}

extern "C" void kernel_launch(void* const* d_in, const int* in_sizes, int n_in,
                              void* d_out, int out_size, void* d_ws, size_t ws_size,
                              hipStream_t stream)
{
  const float* xg = (const float*)d_in[0];
  const float* Wg = (const float*)d_in[1];
  float* out = (float*)d_out;

  const size_t part_b = (size_t)NSLOT*PARTBLK*sizeof(float);   // 32 MB
  const size_t a1_b   = (size_t)IC*OC*NB*sizeof(float);        // 16 MB
  const size_t c_b    = a1_b;                                  // 16 MB
  const size_t v_b    = (size_t)NB*ODF*sizeof(float);          // 256 KB
  const size_t wh_b   = (size_t)IC*ODF*IK*2;                   // 128 MB f16 W

  char* ws = (char*)d_ws;
  float* part = (float*)ws;                  ws += part_b;
  float* a1g  = (float*)ws;                  ws += a1_b;
  float* cg   = (float*)ws;                  ws += c_b;
  float* vbuf = (float*)ws;                  ws += v_b;
  uint4* whg  = (uint4*)ws;
  const bool WH = (part_b + a1_b + c_b + v_b + wh_b) <= ws_size;

  if (WH) {
    caps_gemm0<1><<<NSLOT, 1024, 0, stream>>>(xg, Wg, whg, part);
    caps_reduce<<<NB*OC, 64, 0, stream>>>(part, vbuf);
    caps_agree<1,1><<<512, 1024, 0, stream>>>(xg, Wg, whg, vbuf, a1g, cg);
    caps_saccum<1><<<NSLOT, 1024, 0, stream>>>(xg, Wg, whg, cg, part);
    caps_reduce<<<NB*OC, 64, 0, stream>>>(part, vbuf);
    caps_agree<2,1><<<512, 1024, 0, stream>>>(xg, Wg, whg, vbuf, a1g, cg);
    caps_saccum<1><<<NSLOT, 1024, 0, stream>>>(xg, Wg, whg, cg, part);
    caps_reduce<<<NB*OC, 64, 0, stream>>>(part, out);
  } else {
    caps_gemm0<0><<<NSLOT, 1024, 0, stream>>>(xg, Wg, nullptr, part);
    caps_reduce<<<NB*OC, 64, 0, stream>>>(part, vbuf);
    caps_agree<1,0><<<512, 1024, 0, stream>>>(xg, Wg, nullptr, vbuf, a1g, cg);
    caps_saccum<0><<<NSLOT, 1024, 0, stream>>>(xg, Wg, nullptr, cg, part);
    caps_reduce<<<NB*OC, 64, 0, stream>>>(part, vbuf);
    caps_agree<2,0><<<512, 1024, 0, stream>>>(xg, Wg, nullptr, vbuf, a1g, cg);
    caps_saccum<0><<<NSLOT, 1024, 0, stream>>>(xg, Wg, nullptr, cg, part);
    caps_reduce<<<NB*OC, 64, 0, stream>>>(part, out);
  }
}

// Round 16
// 286.652 us; speedup vs baseline: 1.8205x; 1.4217x over previous
//
#include <hip/hip_runtime.h>
#include <cstdint>

#define NB 32
#define IC 2048
#define IK 16
#define OC 64
#define OD 32
#define ODF (OC*OD)          // 2048 flattened od
#define PARTBLK (16*ODF)     // 32768 floats per slot (16 local b)
#define NCH 128              // 16-i chunks for gemm0/saccum (grid 256)
#define NSLOT (NCH*2)

typedef __fp16 h2 __attribute__((ext_vector_type(2)));
typedef __fp16 h8 __attribute__((ext_vector_type(8)));
typedef float  f4 __attribute__((ext_vector_type(4)));

__device__ __forceinline__ h2 pk2(float a, float b) {
#if __has_builtin(__builtin_amdgcn_cvt_pkrtz)
  return __builtin_amdgcn_cvt_pkrtz(a, b);
#else
  h2 r; r.x = (__fp16)a; r.y = (__fp16)b; return r;
#endif
}
__device__ __forceinline__ float fdot2a(h2 a, h2 b, float c) {
#if __has_builtin(__builtin_amdgcn_fdot2)
  return __builtin_amdgcn_fdot2(a, b, c, false);
#else
  return c + (float)a.x*(float)b.x + (float)a.y*(float)b.y;
#endif
}
__device__ __forceinline__ unsigned int bcu(h2 v){ return __builtin_bit_cast(unsigned int, v); }
__device__ __forceinline__ h2 bch2(unsigned int u){ return __builtin_bit_cast(h2, u); }
__device__ __forceinline__ h8 bch8(uint4 u){ return __builtin_bit_cast(h8, u); }
__device__ __forceinline__ f4 mfma_16x16x32(h8 a, h8 b, f4 c) {
  return __builtin_amdgcn_mfma_f32_16x16x32_f16(a, b, c, 0, 0, 0);
}
__device__ __forceinline__ uint4 packw(const float* wp) {
  const float4 wa = *(const float4*)wp;
  const float4 wb = *(const float4*)(wp + 4);
  uint4 au;
  au.x = bcu(pk2(wa.x, wa.y)); au.y = bcu(pk2(wa.z, wa.w));
  au.z = bcu(pk2(wb.x, wb.y)); au.w = bcu(pk2(wb.z, wb.w));
  return au;
}

// R15 lesson: agree+saccum = 155us/iter == R10's fused 154 regardless of
// fusion/barriers. The invariant pathology was the zero-padded K=16 MFMA with
// HALF-IDLE W loads (lg<2 only). Fix: every kernel now uses the dense gemm0
// lane pattern (all 64 lanes load, full K=32 MFMAs).
//  - agree: sum/diff trick: s=mfma(A,[x1;x2]), d=mfma(A,[x1;-x2]) ->
//    u1.v=(s+d).(v/2), u2.v=(s-d).(v/2). No per-i padding.
//  - saccum: fold c into B: acc=mfma([W1;W2],[c1*x1;c2*x2],acc). Half the
//    MFMAs, no post-scale VALU.

// K0: iter-1 GEMM (c=1/64 exact), two i per MFMA. WH: also emits packed-f16 W
// copy (bh==0 twins) streamed by later passes at half BW.
template<int WH>
__global__ __launch_bounds__(1024)
void caps_gemm0(const float* __restrict__ xg, const float* __restrict__ Wg,
                uint4* __restrict__ Whg, float* __restrict__ part)
{
  __shared__ uint4 x_h[8][2][16];
  const int t = threadIdx.x, w = t >> 6, l = t & 63, lb = l & 15, lg = l >> 4;
  const int bid = blockIdx.x, slot = bid >> 3;
  const int bh = slot & 1;
  const int ci = (bid & 7)*16 + (slot >> 1);     // XCD-grouped twins
  const int i0 = ci*16, bg0 = bh*16;
  const f4 zf = {0.f,0.f,0.f,0.f};
  f4 acc[8];
#pragma unroll
  for (int q = 0; q < 8; ++q) acc[q] = zf;

  for (int g8 = 0; g8 < 16; g8 += 8) {
    if (g8) __syncthreads();
    if (t < 256) {
      const int si = t >> 5, kc2 = (t >> 4) & 1, sb = t & 15;
      const float* xp = &xg[((size_t)(bg0 + sb)*IC + (i0 + g8 + si))*IK + kc2*8];
      x_h[si][kc2][sb] = packw(xp);
    }
    __syncthreads();
#pragma unroll 1
    for (int p = 0; p < 4; ++p) {
      const int isel = lg >> 1, kc = lg & 1, il = p*2 + isel;
      const h8 B = bch8(x_h[il][kc][lb]);
#pragma unroll
      for (int tt = 0; tt < 8; ++tt) {
        const size_t widx = (size_t)(i0 + g8 + il)*ODF + (w*8 + tt)*16 + lb;
        const uint4 au = packw(&Wg[widx*IK + kc*8]);
        if (WH && bh == 0) Whg[widx*2 + kc] = au;
        acc[tt] = mfma_16x16x32(bch8(au), B, acc[tt]);
      }
    }
  }
  float* pp = part + (size_t)(ci*2 + bh)*PARTBLK;
#pragma unroll
  for (int tt = 0; tt < 8; ++tt) {
    float4 st;
    st.x = acc[tt].x*(1.f/64.f); st.y = acc[tt].y*(1.f/64.f);
    st.z = acc[tt].z*(1.f/64.f); st.w = acc[tt].w*(1.f/64.f);
    *(float4*)&pp[(size_t)lb*ODF + (w*8 + tt)*16 + lg*4] = st;
  }
}

// KA: agreement + softmax + coalesced c write, sum/diff dense form.
// grid 512 (8-i chunks x 2 bh), 3 barriers. v held as packed f16 * 0.5.
template<int ITER, int WH>
__global__ __launch_bounds__(1024)
void caps_agree(const float* __restrict__ xg, const float* __restrict__ Wg,
                const uint4* __restrict__ Whg, const float* __restrict__ vin,
                float* __restrict__ a1g, float* __restrict__ cg)
{
  __shared__ uint4 x_h[8][2][16];
  __shared__ float agr[8*64*17];                 // 34.8 KB [ii][o][b]
  const int t = threadIdx.x, w = t >> 6, l = t & 63, lb = l & 15, lg = l >> 4;
  const int bid = blockIdx.x, slot = bid >> 3;
  const int bh = slot & 1;
  const int ci8 = (bid & 7)*32 + (slot >> 1);    // 0..255
  const int i0 = ci8*8, bg0 = bh*16;
  const f4 zf = {0.f,0.f,0.f,0.f};

  if (t < 256) {
    const int si = t >> 5, kc2 = (t >> 4) & 1, sb = t & 15;
    const float* xp = &xg[((size_t)(bg0 + sb)*IC + (i0 + si))*IK + kc2*8];
    x_h[si][kc2][sb] = packw(xp);
  }
  // v*0.5 as packed f16 (16 regs), i-invariant
  unsigned int vh[16];
#pragma unroll
  for (int tt = 0; tt < 8; ++tt) {
    const int o = w*4 + (tt >> 1);
    const float4 vv = *(const float4*)
      &vin[((size_t)(bg0 + lb)*OC + o)*OD + (tt & 1)*16 + lg*4];
    vh[tt*2]   = bcu(pk2(0.5f*vv.x, 0.5f*vv.y));
    vh[tt*2+1] = bcu(pk2(0.5f*vv.z, 0.5f*vv.w));
  }
  __syncthreads();

  const int isel = lg >> 1, kc = lg & 1;
  const unsigned int msk = (lg >= 2) ? 0x80008000u : 0u;   // negate i2 K-half

#pragma unroll 1
  for (int p = 0; p < 4; ++p) {                  // i-pair
    const int iA = i0 + p*2, iB = iA + 1;
    const uint4 bu = x_h[p*2 + isel][kc][lb];
    uint4 bm;
    bm.x = bu.x^msk; bm.y = bu.y^msk; bm.z = bu.z^msk; bm.w = bu.w^msk;
    const h8 Bp = bch8(bu), Bm = bch8(bm);
    float ap1[4] = {0.f,0.f,0.f,0.f}, ap2[4] = {0.f,0.f,0.f,0.f};
#pragma unroll
    for (int tt = 0; tt < 8; ++tt) {
      const size_t widx = (size_t)(iA + isel)*ODF + (w*8 + tt)*16 + lb;
      const uint4 au = WH ? Whg[widx*2 + kc] : packw(&Wg[widx*IK + kc*8]);
      const h8 A = bch8(au);
      const f4 s = mfma_16x16x32(A, Bp, zf);     // u_iA + u_iB
      const f4 d = mfma_16x16x32(A, Bm, zf);     // u_iA - u_iB
      const h2 sh0 = pk2(s.x, s.y), sh1 = pk2(s.z, s.w);
      const h2 dh0 = pk2(d.x, d.y), dh1 = pk2(d.z, d.w);
      const float ds = fdot2a(sh0, bch2(vh[tt*2]), fdot2a(sh1, bch2(vh[tt*2+1]), 0.f));
      const float dd = fdot2a(dh0, bch2(vh[tt*2]), fdot2a(dh1, bch2(vh[tt*2+1]), 0.f));
      ap1[tt >> 1] += ds + dd;                   // u_iA . v
      ap2[tt >> 1] += ds - dd;                   // u_iB . v
    }
#pragma unroll
    for (int q = 0; q < 4; ++q) {
      float a1v = ap1[q], a2v = ap2[q];
      a1v += __shfl_xor(a1v, 16); a1v += __shfl_xor(a1v, 32);
      a2v += __shfl_xor(a2v, 16); a2v += __shfl_xor(a2v, 32);
      if (l < 16) {
        const int o = w*4 + q;
        float b1 = a1v, b2 = a2v;
        if (ITER == 2) {
          b1 += a1g[((size_t)iA*OC + o)*NB + bg0 + lb];
          b2 += a1g[((size_t)iB*OC + o)*NB + bg0 + lb];
        }
        if (ITER == 1) {
          a1g[((size_t)iA*OC + o)*NB + bg0 + lb] = b1;
          a1g[((size_t)iB*OC + o)*NB + bg0 + lb] = b2;
        }
        agr[((p*2)*64 + o)*17 + lb]   = b1;
        agr[((p*2+1)*64 + o)*17 + lb] = b2;
      }
    }
  }
  __syncthreads();
  // batched softmax: 128 (i,b) rows, 8 per wave; c overwrites agr in place
#pragma unroll
  for (int r = 0; r < 8; ++r) {
    const int row = w*8 + r, si = row >> 4, b = row & 15;
    const float a = agr[(si*64 + l)*17 + b];     // o = l
    float m = a;
#pragma unroll
    for (int off = 1; off < 64; off <<= 1) m = fmaxf(m, __shfl_xor(m, off));
    const float e = __expf(a - m);
    float se = e;
#pragma unroll
    for (int off = 1; off < 64; off <<= 1) se += __shfl_xor(se, off);
    agr[(si*64 + l)*17 + b] = e / se;
  }
  __syncthreads();
  // coalesced c flush: [i][o][b], 64B segments
#pragma unroll
  for (int cc = 0; cc < 8; ++cc) {
    const int o = t >> 4, b2 = t & 15;
    cg[((size_t)(i0 + cc)*OC + o)*NB + bg0 + b2] = agr[(cc*64 + o)*17 + b2];
  }
}

// KB: s accumulation — c folded into the B fragment (v_pk_mul_f16), direct
// MFMA accumulate over i-pairs (K=32 dense, half the MFMAs of R15).
template<int WH>
__global__ __launch_bounds__(1024)
void caps_saccum(const float* __restrict__ xg, const float* __restrict__ Wg,
                 const uint4* __restrict__ Whg, const float* __restrict__ cg,
                 float* __restrict__ part)
{
  __shared__ uint4 x_h[8][2][16];
  const int t = threadIdx.x, w = t >> 6, l = t & 63, lb = l & 15, lg = l >> 4;
  const int bid = blockIdx.x, slot = bid >> 3;
  const int bh = slot & 1;
  const int ci = (bid & 7)*16 + (slot >> 1);
  const int i0 = ci*16, bg0 = bh*16;
  const f4 zf = {0.f,0.f,0.f,0.f};
  f4 acc[8];
#pragma unroll
  for (int q = 0; q < 8; ++q) acc[q] = zf;
  const int isel = lg >> 1, kc = lg & 1;

  for (int g8 = 0; g8 < 16; g8 += 8) {
    if (g8) __syncthreads();
    if (t < 256) {
      const int si = t >> 5, kc2 = (t >> 4) & 1, sb = t & 15;
      const float* xp = &xg[((size_t)(bg0 + sb)*IC + (i0 + g8 + si))*IK + kc2*8];
      x_h[si][kc2][sb] = packw(xp);
    }
    __syncthreads();
#pragma unroll 1
    for (int p = 0; p < 4; ++p) {
      const int iA = i0 + g8 + p*2, iB = iA + 1;
      const uint4 bu = x_h[p*2 + isel][kc][lb];
#pragma unroll
      for (int q = 0; q < 4; ++q) {              // o-quad; 2 tiles share o
        const int o = w*4 + q;
        const float c1 = cg[((size_t)iA*OC + o)*NB + bg0 + lb];
        const float c2 = cg[((size_t)iB*OC + o)*NB + bg0 + lb];
        const float cs = (lg < 2) ? c1 : c2;     // my K-half's i
        const h2 cpk = pk2(cs, cs);
        uint4 bs;
        bs.x = bcu(bch2(bu.x)*cpk); bs.y = bcu(bch2(bu.y)*cpk);
        bs.z = bcu(bch2(bu.z)*cpk); bs.w = bcu(bch2(bu.w)*cpk);
        const h8 Bs = bch8(bs);
#pragma unroll
        for (int th = 0; th < 2; ++th) {
          const int tt = q*2 + th;
          const size_t widx = (size_t)(iA + isel)*ODF + (w*8 + tt)*16 + lb;
          const uint4 au = WH ? Whg[widx*2 + kc] : packw(&Wg[widx*IK + kc*8]);
          acc[tt] = mfma_16x16x32(bch8(au), Bs, acc[tt]);   // += c1*uA + c2*uB
        }
      }
    }
  }
  float* pp = part + (size_t)(ci*2 + bh)*PARTBLK;
#pragma unroll
  for (int tt = 0; tt < 8; ++tt) {
    float4 st; st.x = acc[tt].x; st.y = acc[tt].y; st.z = acc[tt].z; st.w = acc[tt].w;
    *(float4*)&pp[(size_t)lb*ODF + (w*8 + tt)*16 + lg*4] = st;
  }
}

// Sum the 256 slots and apply squash (R10-verified).
__global__ __launch_bounds__(64)
void caps_reduce(const float* __restrict__ part, float* __restrict__ vout)
{
  const int r  = blockIdx.x;           // b*OC + o
  const int b  = r >> 6, o = r & 63;
  const int bh = b >> 4, bl = b & 15;
  const int d  = threadIdx.x & 31;
  const int h  = threadIdx.x >> 5;
  const float* p = part + (size_t)bh*PARTBLK + (size_t)bl*ODF + o*OD + d;
  float s = 0.f;
#pragma unroll 4
  for (int q = 0; q < NCH/2; ++q)
    s += p[(size_t)((h*(NCH/2) + q)*2)*PARTBLK];
  s += __shfl_xor(s, 32);
  float n2 = s*s;
#pragma unroll
  for (int off = 1; off < 32; off <<= 1) n2 += __shfl_xor(n2, off);
  const float n = sqrtf(n2);
  const float f = n2 / ((1.f + n2)*(n + 1e-8f));
  if (h == 0) vout[(size_t)r*OD + d] = s*f;
}

extern "C" void kernel_launch(void* const* d_in, const int* in_sizes, int n_in,
                              void* d_out, int out_size, void* d_ws, size_t ws_size,
                              hipStream_t stream)
{
  const float* xg = (const float*)d_in[0];
  const float* Wg = (const float*)d_in[1];
  float* out = (float*)d_out;

  const size_t part_b = (size_t)NSLOT*PARTBLK*sizeof(float);   // 32 MB
  const size_t a1_b   = (size_t)IC*OC*NB*sizeof(float);        // 16 MB
  const size_t c_b    = a1_b;                                  // 16 MB
  const size_t v_b    = (size_t)NB*ODF*sizeof(float);          // 256 KB
  const size_t wh_b   = (size_t)IC*ODF*IK*2;                   // 128 MB f16 W

  char* ws = (char*)d_ws;
  float* part = (float*)ws;                  ws += part_b;
  float* a1g  = (float*)ws;                  ws += a1_b;
  float* cg   = (float*)ws;                  ws += c_b;
  float* vbuf = (float*)ws;                  ws += v_b;
  uint4* whg  = (uint4*)ws;
  const bool WH = (part_b + a1_b + c_b + v_b + wh_b) <= ws_size;

  if (WH) {
    caps_gemm0<1><<<NSLOT, 1024, 0, stream>>>(xg, Wg, whg, part);
    caps_reduce<<<NB*OC, 64, 0, stream>>>(part, vbuf);
    caps_agree<1,1><<<512, 1024, 0, stream>>>(xg, Wg, whg, vbuf, a1g, cg);
    caps_saccum<1><<<NSLOT, 1024, 0, stream>>>(xg, Wg, whg, cg, part);
    caps_reduce<<<NB*OC, 64, 0, stream>>>(part, vbuf);
    caps_agree<2,1><<<512, 1024, 0, stream>>>(xg, Wg, whg, vbuf, a1g, cg);
    caps_saccum<1><<<NSLOT, 1024, 0, stream>>>(xg, Wg, whg, cg, part);
    caps_reduce<<<NB*OC, 64, 0, stream>>>(part, out);
  } else {
    caps_gemm0<0><<<NSLOT, 1024, 0, stream>>>(xg, Wg, nullptr, part);
    caps_reduce<<<NB*OC, 64, 0, stream>>>(part, vbuf);
    caps_agree<1,0><<<512, 1024, 0, stream>>>(xg, Wg, nullptr, vbuf, a1g, cg);
    caps_saccum<0><<<NSLOT, 1024, 0, stream>>>(xg, Wg, nullptr, cg, part);
    caps_reduce<<<NB*OC, 64, 0, stream>>>(part, vbuf);
    caps_agree<2,0><<<512, 1024, 0, stream>>>(xg, Wg, nullptr, vbuf, a1g, cg);
    caps_saccum<0><<<NSLOT, 1024, 0, stream>>>(xg, Wg, nullptr, cg, part);
    caps_reduce<<<NB*OC, 64, 0, stream>>>(part, out);
  }
}